// Round 8
// baseline (395.720 us; speedup 1.0000x reference)
//
#include <hip/hip_runtime.h>
#include <hip/hip_bf16.h>

typedef __attribute__((ext_vector_type(8))) short bf16x8;
typedef __attribute__((ext_vector_type(4))) short short4v;
typedef __attribute__((ext_vector_type(4))) float floatx4;

#define MFMA16(A, B, C) __builtin_amdgcn_mfma_f32_16x16x32_bf16((A), (B), (C), 0, 0, 0)

__device__ inline short bf16bits(float f) {
  __hip_bfloat16 h = __float2bfloat16(f);
  return *reinterpret_cast<short*>(&h);
}
// HW packed f32->bf16 (RNE). No builtin on gfx950 (m240) -> inline asm.
__device__ inline unsigned cvtpk(float lo, float hi) {
  unsigned r;
  asm("v_cvt_pk_bf16_f32 %0, %1, %2" : "=v"(r) : "v"(lo), "v"(hi));
  return r;
}
typedef __attribute__((address_space(3))) char lds_char;
typedef __attribute__((address_space(1))) const char glob_char;
__device__ inline void gll16(const void* g, void* l) {
  __builtin_amdgcn_global_load_lds((glob_char*)g, (lds_char*)l, 16, 0, 0);
}

// ---------------------------------------------------------------------------
// Merged ln1 + wqkv transpose (round 7).
// ---------------------------------------------------------------------------
__global__ __launch_bounds__(256) void ln_qkvtrans_kernel(
    const float* __restrict__ x, __hip_bfloat16* __restrict__ y,
    const float* __restrict__ alpha_p, const float* __restrict__ bias_p,
    const float* __restrict__ wq, const float* __restrict__ wk,
    const float* __restrict__ wv, __hip_bfloat16* __restrict__ wqkvT) {
  __shared__ __align__(16) __hip_bfloat16 tile[64][72];
  const int bid = blockIdx.x;
  const int t = threadIdx.x;
  if (bid < 4096) {
    __shared__ float sred[8];
    const float* xr = x + (long)bid * 1024;
    float v[4];
#pragma unroll
    for (int i = 0; i < 4; i++) v[i] = xr[t * 4 + i];
    float sum = 0.f, sq = 0.f;
#pragma unroll
    for (int i = 0; i < 4; i++) { sum += v[i]; sq += v[i] * v[i]; }
#pragma unroll
    for (int off = 32; off; off >>= 1) {
      sum += __shfl_down(sum, off);
      sq += __shfl_down(sq, off);
    }
    if ((t & 63) == 0) { sred[(t >> 6) * 2] = sum; sred[(t >> 6) * 2 + 1] = sq; }
    __syncthreads();
    sum = sred[0] + sred[2] + sred[4] + sred[6];
    sq = sred[1] + sred[3] + sred[5] + sred[7];
    const float mean = sum * (1.f / 1024.f);
    float var = (sq - 1024.f * mean * mean) * (1.f / 1023.f);
    var = fmaxf(var, 0.f);
    const float denom = sqrtf(var) + 1e-5f;
    const float sc = alpha_p[0] / denom;
    const float beta = bias_p[0];
    __hip_bfloat16* yr = y + (long)bid * 1024;
#pragma unroll
    for (int i = 0; i < 4; i++) yr[t * 4 + i] = __float2bfloat16((v[i] - mean) * sc + beta);
  } else {
    const int tt = bid - 4096;
    const int which = tt >> 8;
    const float* src = which == 0 ? wq : (which == 1 ? wk : wv);
    __hip_bfloat16* dst = wqkvT + (size_t)which * 1024 * 1024;
    const long r0 = (long)((tt >> 4) & 15) * 64, c0 = (long)(tt & 15) * 64;
    for (int i = t; i < 1024; i += 256) {
      int r = i >> 4, c4 = (i & 15) * 4;
      float4 f = *(const float4*)&src[(r0 + r) * 1024 + c0 + c4];
      short4v s;
      s[0] = bf16bits(f.x); s[1] = bf16bits(f.y);
      s[2] = bf16bits(f.z); s[3] = bf16bits(f.w);
      *(short4v*)&tile[r][c4] = s;
    }
    __syncthreads();
    for (int i = t; i < 512; i += 256) {
      int c = i >> 3, r8 = (i & 7) * 8;
      bf16x8 sv;
#pragma unroll
      for (int j = 0; j < 8; j++) sv[j] = *reinterpret_cast<const short*>(&tile[r8 + j][c]);
      *(bf16x8*)&dst[(c0 + c) * 1024 + r0 + r8] = sv;
    }
  }
}

// ---------------------------------------------------------------------------
// Merged stage-B prep kernel (round 6).
// ---------------------------------------------------------------------------
__global__ __launch_bounds__(256) void prep_kernel(
    const __hip_bfloat16* __restrict__ qkv, __hip_bfloat16* __restrict__ vt,
    const float* __restrict__ wo, __hip_bfloat16* __restrict__ woT,
    const int* __restrict__ mask, float* __restrict__ addm,
    int* __restrict__ flags) {
  __shared__ __align__(16) __hip_bfloat16 tile[64][72];
  __shared__ int ok[4];
  const int bid = blockIdx.x;
  if (bid < 1024) {
    const int bh = bid >> 5, b = bh >> 4, h = bh & 15;
    const long s0 = (long)(bid & 31) * 64;
    const __hip_bfloat16* src = qkv + ((long)b * 2048 + s0) * 3072 + 2048 + h * 64;
    for (int i = threadIdx.x; i < 512; i += 256) {
      int s = i >> 3, d8 = (i & 7) * 8;
      *(uint4*)&tile[s][d8] = *(const uint4*)&src[(long)s * 3072 + d8];
    }
    __syncthreads();
    __hip_bfloat16* dstb = vt + (long)bh * 64 * 2048 + s0;
    for (int i = threadIdx.x; i < 512; i += 256) {
      int d = i >> 3, s8 = (i & 7) * 8;
      bf16x8 sv;
#pragma unroll
      for (int j = 0; j < 8; j++) sv[j] = *reinterpret_cast<const short*>(&tile[s8 + j][d]);
      *(bf16x8*)&dstb[(long)d * 2048 + s8] = sv;
    }
  } else if (bid < 1280) {
    const int t = bid - 1024;
    const long r0 = (long)(t >> 4) * 64, c0 = (long)(t & 15) * 64;
    for (int i = threadIdx.x; i < 1024; i += 256) {
      int r = i >> 4, c4 = (i & 15) * 4;
      float4 f = *(const float4*)&wo[(r0 + r) * 1024 + c0 + c4];
      short4v s;
      s[0] = bf16bits(f.x); s[1] = bf16bits(f.y);
      s[2] = bf16bits(f.z); s[3] = bf16bits(f.w);
      *(short4v*)&tile[r][c4] = s;
    }
    __syncthreads();
    for (int i = threadIdx.x; i < 512; i += 256) {
      int c = i >> 3, r8 = (i & 7) * 8;
      bf16x8 sv;
#pragma unroll
      for (int j = 0; j < 8; j++) sv[j] = *reinterpret_cast<const short*>(&tile[r8 + j][c]);
      *(bf16x8*)&woT[(c0 + c) * 1024 + r0 + r8] = sv;
    }
  } else {
    const int i = (bid - 1280) * 256 + threadIdx.x;
    const int mv = mask[i];
    addm[i] = mv ? 0.f : -1e30f;
    const unsigned long long bal = __ballot(mv != 0);
    if ((threadIdx.x & 63) == 0) ok[threadIdx.x >> 6] = (bal == ~0ull) ? 1 : 0;
    __syncthreads();
    if (threadIdx.x == 0) flags[bid - 1280] = ok[0] & ok[1] & ok[2] & ok[3];
  }
}

// ---------------------------------------------------------------------------
// Merged per-half FFN weight transpose (round 6).
// ---------------------------------------------------------------------------
__global__ __launch_bounds__(256) void wtrans_kernel(
    const float* __restrict__ w1c, const float* __restrict__ w2c,
    __hip_bfloat16* __restrict__ w1Th, __hip_bfloat16* __restrict__ w2Th) {
  __shared__ __align__(16) __hip_bfloat16 tile[64][72];
  const int bid = blockIdx.x;
  const float* src;
  __hip_bfloat16* dst;
  int R, ldS;
  long r0, c0;
  if (bid < 512) {
    src = w1c; dst = w1Th; R = 1024; ldS = 4096;
    r0 = (long)(bid >> 5) * 64; c0 = (long)(bid & 31) * 64;
  } else {
    const int t = bid - 512;
    src = w2c; dst = w2Th; R = 2048; ldS = 1024;
    r0 = (long)(t >> 4) * 64; c0 = (long)(t & 15) * 64;
  }
  for (int i = threadIdx.x; i < 1024; i += 256) {
    int r = i >> 4, c4 = (i & 15) * 4;
    float4 f = *(const float4*)&src[(r0 + r) * ldS + c0 + c4];
    short4v s;
    s[0] = bf16bits(f.x); s[1] = bf16bits(f.y);
    s[2] = bf16bits(f.z); s[3] = bf16bits(f.w);
    *(short4v*)&tile[r][c4] = s;
  }
  __syncthreads();
  for (int i = threadIdx.x; i < 512; i += 256) {
    int c = i >> 3, r8 = (i & 7) * 8;
    bf16x8 sv;
#pragma unroll
    for (int j = 0; j < 8; j++) sv[j] = *reinterpret_cast<const short*>(&tile[r8 + j][c]);
    *(bf16x8*)&dst[(c0 + c) * R + r0 + r8] = sv;
  }
}

// ---------------------------------------------------------------------------
// d_out = x1 + b2 (broadcast over rows), fp32
// ---------------------------------------------------------------------------
__global__ __launch_bounds__(256) void bias_add_kernel(
    const float* __restrict__ x1, const float* __restrict__ b2,
    float* __restrict__ out) {
  const int i = (blockIdx.x * 256 + threadIdx.x) * 4;
  float4 v = *(const float4*)&x1[i];
  const float4 bb = *(const float4*)&b2[i & 1023];
  v.x += bb.x; v.y += bb.y; v.z += bb.z; v.w += bb.w;
  *(float4*)&out[i] = v;
}

// ---------------------------------------------------------------------------
// LayerNorm: 1 block per 1024-elem row. ddof=1, eps added to std. fp32 -> bf16.
// ---------------------------------------------------------------------------
__global__ __launch_bounds__(256) void ln_kernel(
    const float* __restrict__ x, __hip_bfloat16* __restrict__ y,
    const float* __restrict__ alpha_p, const float* __restrict__ bias_p) {
  __shared__ float sred[8];
  const long row = blockIdx.x;
  const int t = threadIdx.x;
  const float* xr = x + row * 1024;
  float v[4];
#pragma unroll
  for (int i = 0; i < 4; i++) v[i] = xr[t * 4 + i];
  float sum = 0.f, sq = 0.f;
#pragma unroll
  for (int i = 0; i < 4; i++) { sum += v[i]; sq += v[i] * v[i]; }
#pragma unroll
  for (int off = 32; off; off >>= 1) {
    sum += __shfl_down(sum, off);
    sq += __shfl_down(sq, off);
  }
  if ((t & 63) == 0) { sred[(t >> 6) * 2] = sum; sred[(t >> 6) * 2 + 1] = sq; }
  __syncthreads();
  sum = sred[0] + sred[2] + sred[4] + sred[6];
  sq = sred[1] + sred[3] + sred[5] + sred[7];
  const float mean = sum * (1.f / 1024.f);
  float var = (sq - 1024.f * mean * mean) * (1.f / 1023.f);
  var = fmaxf(var, 0.f);
  const float denom = sqrtf(var) + 1e-5f;
  const float sc = alpha_p[0] / denom;
  const float beta = bias_p[0];
  __hip_bfloat16* yr = y + row * 1024;
#pragma unroll
  for (int i = 0; i < 4; i++) yr[t * 4 + i] = __float2bfloat16((v[i] - mean) * sc + beta);
}

// ---------------------------------------------------------------------------
// bf16 GEMM, B pre-transposed: 128x128 tile, BK=32, dbuf + XCD swizzle.
// (Kept for shapes where 3+ blocks/CU matters; no current users at BK=32
// except fallback.) EPI as before.
// ---------------------------------------------------------------------------
template <int EPI>
__global__ __launch_bounds__(256) void gemm_bt_kernel(
    const __hip_bfloat16* __restrict__ A, const __hip_bfloat16* __restrict__ Bt,
    void* __restrict__ Cv, const float* __restrict__ bias,
    const float* __restrict__ res, int M, int N, int K) {
  __shared__ __align__(16) __hip_bfloat16 lA[2][128 * 32];
  __shared__ __align__(16) __hip_bfloat16 lB[2][128 * 32];
  const int tid = threadIdx.x;
  const int wave = tid >> 6, lane = tid & 63;
  const int quad = lane >> 4, l16 = lane & 15;
  const int wm = wave >> 1, wn = wave & 1;

  const int gx = gridDim.x;
  const int nwg = gx * gridDim.y;
  int bid = blockIdx.y * gx + blockIdx.x;
  bid = (bid & 7) * (nwg >> 3) + (bid >> 3);
  const long m0 = (long)(bid / gx) * 128;
  const long n0 = (long)(bid % gx) * 128;

  const int rA0 = tid >> 2, cA0 = (tid & 3) * 8;
  const int rA1 = (tid + 256) >> 2, cA1 = ((tid + 256) & 3) * 8;

  floatx4 acc[4][4];
#pragma unroll
  for (int i = 0; i < 4; i++)
#pragma unroll
    for (int j = 0; j < 4; j++) acc[i][j] = (floatx4){0.f, 0.f, 0.f, 0.f};

  const __hip_bfloat16* Ab = A + m0 * K;
  const __hip_bfloat16* Bb = Bt + n0 * K;

  gll16(&Ab[(long)rA0 * K + cA0], &lA[0][wave * 512]);
  gll16(&Ab[(long)rA1 * K + cA1], &lA[0][2048 + wave * 512]);
  gll16(&Bb[(long)rA0 * K + cA0], &lB[0][wave * 512]);
  gll16(&Bb[(long)rA1 * K + cA1], &lB[0][2048 + wave * 512]);

  int cur = 0;
  for (int k0 = 0; k0 < K; k0 += 32) {
    __syncthreads();
    if (k0 + 32 < K) {
      const int nxt = cur ^ 1;
      gll16(&Ab[(long)rA0 * K + k0 + 32 + cA0], &lA[nxt][wave * 512]);
      gll16(&Ab[(long)rA1 * K + k0 + 32 + cA1], &lA[nxt][2048 + wave * 512]);
      gll16(&Bb[(long)rA0 * K + k0 + 32 + cA0], &lB[nxt][wave * 512]);
      gll16(&Bb[(long)rA1 * K + k0 + 32 + cA1], &lB[nxt][2048 + wave * 512]);
    }
    bf16x8 af[4], bfr[4];
#pragma unroll
    for (int mi = 0; mi < 4; mi++)
      af[mi] = *(const bf16x8*)&lA[cur][(wm * 64 + mi * 16 + l16) * 32 + quad * 8];
#pragma unroll
    for (int ni = 0; ni < 4; ni++)
      bfr[ni] = *(const bf16x8*)&lB[cur][(wn * 64 + ni * 16 + l16) * 32 + quad * 8];
#pragma unroll
    for (int mi = 0; mi < 4; mi++)
#pragma unroll
      for (int ni = 0; ni < 4; ni++)
        acc[mi][ni] = MFMA16(af[mi], bfr[ni], acc[mi][ni]);
    cur ^= 1;
  }

#pragma unroll
  for (int mi = 0; mi < 4; mi++) {
#pragma unroll
    for (int ni = 0; ni < 4; ni++) {
#pragma unroll
      for (int r = 0; r < 4; r++) {
        const long row = m0 + wm * 64 + mi * 16 + quad * 4 + r;
        const long col = n0 + wn * 64 + ni * 16 + l16;
        const long idx = row * N + col;
        float v = acc[mi][ni][r];
        if (EPI == 0) {
          ((__hip_bfloat16*)Cv)[idx] = __float2bfloat16(v);
        } else if (EPI == 1) {
          ((float*)Cv)[idx] = v + res[idx];
        } else if (EPI == 2) {
          v += bias[col];
          ((__hip_bfloat16*)Cv)[idx] = __float2bfloat16(fmaxf(v, 0.f));
        } else if (EPI == 3) {
          float* Cf = (float*)Cv;
          Cf[idx] = Cf[idx] + v;
        }
      }
    }
  }
}

// ---------------------------------------------------------------------------
// 128x128 tile, BK=64, XOR-swizzled LDS (round 7). Round 8: now also used
// for the qkv GEMM (768 blocks at 64 KB -> 2/CU; BK=64 halves barriers).
// ---------------------------------------------------------------------------
template <int EPI>
__global__ __launch_bounds__(256) void gemm_bt_k64_kernel(
    const __hip_bfloat16* __restrict__ A, const __hip_bfloat16* __restrict__ Bt,
    void* __restrict__ Cv, const float* __restrict__ bias,
    const float* __restrict__ res, int M, int N, int K) {
  __shared__ __align__(16) __hip_bfloat16 lA[2][128 * 64];
  __shared__ __align__(16) __hip_bfloat16 lB[2][128 * 64];
  const int tid = threadIdx.x;
  const int wave = tid >> 6, lane = tid & 63;
  const int quad = lane >> 4, l16 = lane & 15;
  const int wm = wave >> 1, wn = wave & 1;

  const int gx = gridDim.x;
  const int nwg = gx * gridDim.y;
  int bid = blockIdx.y * gx + blockIdx.x;
  bid = (bid & 7) * (nwg >> 3) + (bid >> 3);
  const long m0 = (long)(bid / gx) * 128;
  const long n0 = (long)(bid % gx) * 128;

  const int srow = lane >> 3;               // row within 8-row chunk
  const int cg = (lane & 7) ^ srow;         // pre-swizzled global k-group

  floatx4 acc[4][4];
#pragma unroll
  for (int i = 0; i < 4; i++)
#pragma unroll
    for (int j = 0; j < 4; j++) acc[i][j] = (floatx4){0.f, 0.f, 0.f, 0.f};

  const __hip_bfloat16* Ab = A + m0 * K;
  const __hip_bfloat16* Bb = Bt + n0 * K;

#pragma unroll
  for (int j = 0; j < 4; ++j) {
    const int c = wave + j * 4;
    gll16(&Ab[(long)(c * 8 + srow) * K + cg * 8], &lA[0][c * 512]);
    gll16(&Bb[(long)(c * 8 + srow) * K + cg * 8], &lB[0][c * 512]);
  }

  int cur = 0;
  for (int k0 = 0; k0 < K; k0 += 64) {
    __syncthreads();
    if (k0 + 64 < K) {
      const int nxt = cur ^ 1;
#pragma unroll
      for (int j = 0; j < 4; ++j) {
        const int c = wave + j * 4;
        gll16(&Ab[(long)(c * 8 + srow) * K + k0 + 64 + cg * 8], &lA[nxt][c * 512]);
        gll16(&Bb[(long)(c * 8 + srow) * K + k0 + 64 + cg * 8], &lB[nxt][c * 512]);
      }
    }
#pragma unroll
    for (int ks = 0; ks < 2; ++ks) {
      bf16x8 af[4], bfr[4];
#pragma unroll
      for (int mi = 0; mi < 4; mi++) {
        const int row = wm * 64 + mi * 16 + l16;
        af[mi] = *(const bf16x8*)&lA[cur][row * 64 +
                                          (((ks * 4 + quad) ^ (l16 & 7)) * 8)];
      }
#pragma unroll
      for (int ni = 0; ni < 4; ni++) {
        const int row = wn * 64 + ni * 16 + l16;
        bfr[ni] = *(const bf16x8*)&lB[cur][row * 64 +
                                           (((ks * 4 + quad) ^ (l16 & 7)) * 8)];
      }
#pragma unroll
      for (int mi = 0; mi < 4; mi++)
#pragma unroll
        for (int ni = 0; ni < 4; ni++)
          acc[mi][ni] = MFMA16(af[mi], bfr[ni], acc[mi][ni]);
    }
    cur ^= 1;
  }

#pragma unroll
  for (int mi = 0; mi < 4; mi++) {
#pragma unroll
    for (int ni = 0; ni < 4; ni++) {
#pragma unroll
      for (int r = 0; r < 4; r++) {
        const long row = m0 + wm * 64 + mi * 16 + quad * 4 + r;
        const long col = n0 + wn * 64 + ni * 16 + l16;
        const long idx = row * N + col;
        float v = acc[mi][ni][r];
        if (EPI == 0) {
          ((__hip_bfloat16*)Cv)[idx] = __float2bfloat16(v);
        } else if (EPI == 1) {
          ((float*)Cv)[idx] = v + res[idx];
        } else if (EPI == 2) {
          v += bias[col];
          ((__hip_bfloat16*)Cv)[idx] = __float2bfloat16(fmaxf(v, 0.f));
        } else if (EPI == 3) {
          float* Cf = (float*)Cv;
          Cf[idx] = Cf[idx] + v;
        }
      }
    }
  }
}

// ---------------------------------------------------------------------------
// 128x64-tile variant for N=1024 GEMMs (wo, ffn2): BK=64 swizzled (round 6).
// ---------------------------------------------------------------------------
template <int EPI>
__global__ __launch_bounds__(256) void gemm64_bt_kernel(
    const __hip_bfloat16* __restrict__ A, const __hip_bfloat16* __restrict__ Bt,
    void* __restrict__ Cv, const float* __restrict__ bias,
    const float* __restrict__ res, int M, int N, int K) {
  __shared__ __align__(16) __hip_bfloat16 lA[2][128 * 64];
  __shared__ __align__(16) __hip_bfloat16 lB[2][64 * 64];
  const int tid = threadIdx.x;
  const int wave = tid >> 6, lane = tid & 63;
  const int quad = lane >> 4, l16 = lane & 15;
  const int wm = wave >> 1, wn = wave & 1;

  const int gx = gridDim.x;
  const int nwg = gx * gridDim.y;
  int bid = blockIdx.y * gx + blockIdx.x;
  bid = (bid & 7) * (nwg >> 3) + (bid >> 3);
  const long m0 = (long)(bid / gx) * 128;
  const long n0 = (long)(bid % gx) * 64;

  const int srow = lane >> 3;
  const int cg = (lane & 7) ^ srow;

  floatx4 acc[4][2];
#pragma unroll
  for (int i = 0; i < 4; i++)
#pragma unroll
    for (int j = 0; j < 2; j++) acc[i][j] = (floatx4){0.f, 0.f, 0.f, 0.f};

  const __hip_bfloat16* Ab = A + m0 * K;
  const __hip_bfloat16* Bb = Bt + n0 * K;

#pragma unroll
  for (int j = 0; j < 4; ++j) {
    const int c = wave + j * 4;
    gll16(&Ab[(long)(c * 8 + srow) * K + cg * 8], &lA[0][c * 512]);
  }
#pragma unroll
  for (int j = 0; j < 2; ++j) {
    const int c = wave + j * 4;
    gll16(&Bb[(long)(c * 8 + srow) * K + cg * 8], &lB[0][c * 512]);
  }

  int cur = 0;
  for (int k0 = 0; k0 < K; k0 += 64) {
    __syncthreads();
    if (k0 + 64 < K) {
      const int nxt = cur ^ 1;
#pragma unroll
      for (int j = 0; j < 4; ++j) {
        const int c = wave + j * 4;
        gll16(&Ab[(long)(c * 8 + srow) * K + k0 + 64 + cg * 8], &lA[nxt][c * 512]);
      }
#pragma unroll
      for (int j = 0; j < 2; ++j) {
        const int c = wave + j * 4;
        gll16(&Bb[(long)(c * 8 + srow) * K + k0 + 64 + cg * 8], &lB[nxt][c * 512]);
      }
    }
#pragma unroll
    for (int ks = 0; ks < 2; ++ks) {
      bf16x8 af[4], bfr[2];
#pragma unroll
      for (int mi = 0; mi < 4; mi++) {
        const int row = wm * 64 + mi * 16 + l16;
        af[mi] = *(const bf16x8*)&lA[cur][row * 64 +
                                          (((ks * 4 + quad) ^ (l16 & 7)) * 8)];
      }
#pragma unroll
      for (int ni = 0; ni < 2; ni++) {
        const int row = wn * 32 + ni * 16 + l16;
        bfr[ni] = *(const bf16x8*)&lB[cur][row * 64 +
                                           (((ks * 4 + quad) ^ (l16 & 7)) * 8)];
      }
#pragma unroll
      for (int mi = 0; mi < 4; mi++)
#pragma unroll
        for (int ni = 0; ni < 2; ni++)
          acc[mi][ni] = MFMA16(af[mi], bfr[ni], acc[mi][ni]);
    }
    cur ^= 1;
  }

#pragma unroll
  for (int mi = 0; mi < 4; mi++) {
#pragma unroll
    for (int ni = 0; ni < 2; ni++) {
#pragma unroll
      for (int r = 0; r < 4; r++) {
        const long row = m0 + wm * 64 + mi * 16 + quad * 4 + r;
        const long col = n0 + wn * 32 + ni * 16 + l16;
        const long idx = row * N + col;
        float v = acc[mi][ni][r];
        if (EPI == 1) {
          ((float*)Cv)[idx] = v + res[idx];
        } else if (EPI == 3) {
          float* Cf = (float*)Cv;
          Cf[idx] = Cf[idx] + v;
        }
      }
    }
  }
}

// ---------------------------------------------------------------------------
// Flash attention. Rounds 1-7: 104 -> 98 -> 87 -> 87 -> 75 us.
// Round 8 (q-row doubling): each wave now owns 32 q-rows (two 16-row
// fragments f=0,1); block covers 128 rows; grid halves to (16,32)=512 =
// 2 blocks/CU. Per tile: K/V staging + barrier amortized over 2x MFMA
// (16 -> 32 per wave), and the two fragments' softmax chains are INDEPENDENT
// -> ILP replaces the lost TLP (T15 mechanism). K/V re-read traffic halves.
// lP grows to 32 rows/wave (16 KB); LDS 48 KB (2/CU -> 96 KB used).
// Spill watch: WRITE_SIZE must stay 8192.
// ---------------------------------------------------------------------------
__global__ __launch_bounds__(256) void attn_kernel(
    const __hip_bfloat16* __restrict__ qkv, const __hip_bfloat16* __restrict__ vt,
    const float* __restrict__ addm, const int* __restrict__ flags,
    __hip_bfloat16* __restrict__ ctx) {
  __shared__ __align__(16) __hip_bfloat16 lK[2][64 * 64];
  __shared__ __align__(16) __hip_bfloat16 lV[2][64 * 64];
  __shared__ __align__(16) __hip_bfloat16 lP[4][32 * 64];  // wave-private P^T
  const int tid = threadIdx.x, wave = tid >> 6, lane = tid & 63;
  const int quad = lane >> 4, l16 = lane & 15;
  const int bh = blockIdx.y, b = bh >> 4, h = bh & 15;
  const int q0 = blockIdx.x * 128 + wave * 32;
  const float cs = 0.18033688011112042f;   // log2(e)/sqrt(64)
  const float inv_cs = 5.545177444479562f; // sqrt(64)/log2(e)

  const __hip_bfloat16* kb = qkv + (long)b * 2048 * 3072 + 1024 + h * 64;
  const __hip_bfloat16* vb = vt + (long)bh * 64 * 2048;
  const float* am = addm + b * 2048;

  int fm = 1;
#pragma unroll
  for (int i = 0; i < 8; ++i) fm &= flags[b * 8 + i];
  const bool fast = (fm != 0);

  bf16x8 bq[2][2];
#pragma unroll
  for (int f = 0; f < 2; ++f) {
    const long qoff = ((long)b * 2048 + q0 + f * 16 + l16) * 3072 + h * 64;
    bq[f][0] = *(const bf16x8*)&qkv[qoff + quad * 8];
    bq[f][1] = *(const bf16x8*)&qkv[qoff + 32 + quad * 8];
  }

  const int srow = lane >> 3;
  const int cslot = lane & 7;
  const int cg = cslot ^ srow;
  const int rbase = wave * 16 + srow;

  // P-buffer addresses (bytes within this wave's 4 KB region)
  char* const pbase = (char*)&lP[wave][0];
  const int pswz = l16 & 7;

  floatx4 o[2][4];
#pragma unroll
  for (int f = 0; f < 2; ++f)
#pragma unroll
    for (int mi = 0; mi < 4; mi++) o[f][mi] = (floatx4){0.f, 0.f, 0.f, 0.f};
  float mrow[2] = {10.0f, 10.0f}, lrow[2] = {0.f, 0.f};

  // prologue: stage tile 0 into buffer 0
#pragma unroll
  for (int j = 0; j < 2; ++j) {
    const int rloc = rbase + j * 8;
    gll16(kb + (long)rloc * 3072 + cg * 8, &lK[0][(wave * 16 + j * 8) * 64]);
    gll16(vb + (long)rloc * 2048 + cg * 8, &lV[0][(wave * 16 + j * 8) * 64]);
  }

  int cur = 0;
  for (int t = 0; t < 32; ++t) {
    __syncthreads();
    if (t + 1 < 32) {
      const int nxt = cur ^ 1;
#pragma unroll
      for (int j = 0; j < 2; ++j) {
        const int rloc = rbase + j * 8;
        gll16(kb + (long)((t + 1) * 64 + rloc) * 3072 + cg * 8,
              &lK[nxt][(wave * 16 + j * 8) * 64]);
        gll16(vb + (long)rloc * 2048 + (t + 1) * 64 + cg * 8,
              &lV[nxt][(wave * 16 + j * 8) * 64]);
      }
    }
    const __hip_bfloat16* lKc = lK[cur];
    const __hip_bfloat16* lVc = lV[cur];

    float tms[2], rs[2];
#pragma unroll
    for (int f = 0; f < 2; ++f) {
      floatx4 c[4];
      __builtin_amdgcn_s_setprio(1);
#pragma unroll
      for (int g = 0; g < 4; ++g) {
        const bf16x8 a0 =
            *(const bf16x8*)&lKc[(g * 16 + l16) * 64 + ((quad) ^ (l16 & 7)) * 8];
        const bf16x8 a1 =
            *(const bf16x8*)&lKc[(g * 16 + l16) * 64 + ((4 + quad) ^ (l16 & 7)) * 8];
        floatx4 cc = {0.f, 0.f, 0.f, 0.f};
        cc = MFMA16(a0, bq[f][0], cc);
        cc = MFMA16(a1, bq[f][1], cc);
        c[g] = cc;
      }
      __builtin_amdgcn_s_setprio(0);

      if (!fast) {
#pragma unroll
        for (int g = 0; g < 4; ++g) {
          const float4 a4 = *(const float4*)&am[t * 64 + g * 16 + quad * 4];
          c[g][0] = fmaf(a4.x, inv_cs, c[g][0]);
          c[g][1] = fmaf(a4.y, inv_cs, c[g][1]);
          c[g][2] = fmaf(a4.z, inv_cs, c[g][2]);
          c[g][3] = fmaf(a4.w, inv_cs, c[g][3]);
        }
      }

      // speculative P with the OLD running max
      const float mneg = -mrow[f];
      float p[4][4];
#pragma unroll
      for (int g = 0; g < 4; ++g)
#pragma unroll
        for (int r = 0; r < 4; ++r)
          p[g][r] = __builtin_amdgcn_exp2f(fmaf(c[g][r], cs, mneg));

      // pack and write to this fragment's rows of the wave P-buffer
      const int prow = (f * 16 + l16) * 128;
#pragma unroll
      for (int g = 0; g < 4; ++g) {
        uint2 w2;
        w2.x = cvtpk(p[g][0], p[g][1]);
        w2.y = cvtpk(p[g][2], p[g][3]);
        const int slot16 = (g * 2 + (quad >> 1)) ^ pswz;
        *(uint2*)(pbase + prow + (slot16 << 4) + ((quad & 1) << 3)) = w2;
      }

      // tile row-max reduce (independent chain per fragment)
      const float m0 = fmaxf(fmaxf(c[0][0], c[0][1]), c[0][2]);
      const float m1 = fmaxf(fmaxf(c[0][3], c[1][0]), c[1][1]);
      const float m2 = fmaxf(fmaxf(c[1][2], c[1][3]), c[2][0]);
      const float m3 = fmaxf(fmaxf(c[2][1], c[2][2]), c[2][3]);
      const float m4 = fmaxf(fmaxf(c[3][0], c[3][1]), c[3][2]);
      float tm = fmaxf(fmaxf(fmaxf(m0, m1), fmaxf(m2, m3)), fmaxf(m4, c[3][3]));
      tm = fmaxf(tm, __shfl_xor(tm, 16));
      tm = fmaxf(tm, __shfl_xor(tm, 32));
      tms[f] = tm * cs;

      const float s0 = (p[0][0] + p[0][1]) + (p[0][2] + p[0][3]);
      const float s1 = (p[1][0] + p[1][1]) + (p[1][2] + p[1][3]);
      const float s2 = (p[2][0] + p[2][1]) + (p[2][2] + p[2][3]);
      const float s3 = (p[3][0] + p[3][1]) + (p[3][2] + p[3][3]);
      float r = (s0 + s1) + (s2 + s3);
      r += __shfl_xor(r, 16);
      r += __shfl_xor(r, 32);
      rs[f] = r;
    }

    // PV for both fragments
#pragma unroll
    for (int f = 0; f < 2; ++f) {
      const int prow = (f * 16 + l16) * 128;
#pragma unroll
      for (int ss = 0; ss < 2; ++ss) {
        const bf16x8 bp = *(const bf16x8*)(pbase + prow +
                                           ((((ss << 2) + quad) ^ pswz) << 4));
        __builtin_amdgcn_s_setprio(1);
#pragma unroll
        for (int mi = 0; mi < 4; ++mi) {
          const bf16x8 av = *(const bf16x8*)&lVc[(mi * 16 + l16) * 64 +
                                                 ((ss * 4 + quad) ^ (l16 & 7)) * 8];
          o[f][mi] = MFMA16(av, bp, o[f][mi]);
        }
        __builtin_amdgcn_s_setprio(0);
      }
    }

#pragma unroll
    for (int f = 0; f < 2; ++f) {
      lrow[f] += rs[f];
      if (__any(tms[f] > mrow[f] + 8.f)) {
        const float mnew = fmaxf(mrow[f], tms[f]);
        const float alpha = __builtin_amdgcn_exp2f(mrow[f] - mnew);
        mrow[f] = mnew;
        lrow[f] *= alpha;
#pragma unroll
        for (int mi = 0; mi < 4; mi++) o[f][mi] *= alpha;
      }
    }
    cur ^= 1;
  }

#pragma unroll
  for (int f = 0; f < 2; ++f) {
    const float inv_l = 1.f / lrow[f];
    const long cb = ((long)b * 2048 + q0 + f * 16 + l16) * 1024 + h * 64;
#pragma unroll
    for (int mi = 0; mi < 4; mi++) {
      uint2 st;
      st.x = cvtpk(o[f][mi][0] * inv_l, o[f][mi][1] * inv_l);
      st.y = cvtpk(o[f][mi][2] * inv_l, o[f][mi][3] * inv_l);
      *(uint2*)&ctx[cb + mi * 16 + quad * 4] = st;
    }
  }
}

// ---------------------------------------------------------------------------
// ws plan (peak 32 MiB) + d_out (16 MiB) as scratch:
//  A: ln_qkvtrans: ln1 x->xn(d_out[0,8)) + wqkvT ws[24,30);
//     qkv-gemm-k64 -> qkv ws[0,24)
//  B: prep: vtrans -> vtb ws[24,32); woT -> d_out[8,10); mask -> addm+flags;
//     attn (512 blocks, 128 q-rows/block) -> ctxb(d_out[0,8))
//  C: wo-gemm64(ctxb,woT)+x -> x1 f32 ws[0,16)  (EPI1)
//  D: ln2 x1 -> xn2(d_out[0,8))
//  E c=0..1: wtrans; ffn1-k64(+b1,relu) -> hc ws[16,32); ffn2-gemm64 (EPI3)
//  F: bias_add: d_out = x1 + b2
//  13 launches.
// ---------------------------------------------------------------------------
extern "C" void kernel_launch(void* const* d_in, const int* in_sizes, int n_in,
                              void* d_out, int out_size, void* d_ws, size_t ws_size,
                              hipStream_t stream) {
  const float* x = (const float*)d_in[0];
  const int* mask = (const int*)d_in[1];
  const float* wq = (const float*)d_in[2];
  const float* wk = (const float*)d_in[3];
  const float* wv = (const float*)d_in[4];
  const float* wo = (const float*)d_in[5];
  const float* w1 = (const float*)d_in[6];
  const float* b1 = (const float*)d_in[7];
  const float* w2 = (const float*)d_in[8];
  const float* b2 = (const float*)d_in[9];
  const float* alpha1 = (const float*)d_in[10];
  const float* bias1 = (const float*)d_in[11];
  const float* alpha2 = (const float*)d_in[12];
  const float* bias2 = (const float*)d_in[13];

  char* ws = (char*)d_ws;
  char* dob = (char*)d_out;
  const size_t MiB = 1048576;
  __hip_bfloat16* qkv   = (__hip_bfloat16*)(ws + 0);          // [0,24)
  __hip_bfloat16* wqkvT = (__hip_bfloat16*)(ws + 24 * MiB);   // [24,30)
  __hip_bfloat16* vtb   = (__hip_bfloat16*)(ws + 24 * MiB);   // [24,32)
  float*          x1    = (float*)(ws + 0);                   // [0,16) f32
  __hip_bfloat16* hc    = (__hip_bfloat16*)(ws + 16 * MiB);   // [16,32)
  __hip_bfloat16* xn    = (__hip_bfloat16*)d_out;             // d_out[0,8) bf16
  __hip_bfloat16* ctxb  = (__hip_bfloat16*)d_out;
  __hip_bfloat16* xn2   = (__hip_bfloat16*)d_out;
  __hip_bfloat16* woT   = (__hip_bfloat16*)(dob + 8 * MiB);   // d_out[8,10)
  __hip_bfloat16* w1Th  = (__hip_bfloat16*)(dob + 8 * MiB);   // d_out[8,12)
  __hip_bfloat16* w2Th  = (__hip_bfloat16*)(dob + 12 * MiB);  // d_out[12,16)
  float*          addm  = (float*)(dob + 12 * MiB);           // d_out[12M,+16K)
  int*            flags = (int*)(dob + 12 * MiB + 16 * 1024); // 64 B after addm

  const dim3 b256(256);
  // Stage A (merged ln1 + wqkv transpose; qkv GEMM now BK=64)
  ln_qkvtrans_kernel<<<4864, b256, 0, stream>>>(x, xn, alpha1, bias1,
                                                wq, wk, wv, wqkvT);
  gemm_bt_k64_kernel<0><<<dim3(24, 32), b256, 0, stream>>>(xn, wqkvT, qkv,
                                                           nullptr, nullptr,
                                                           4096, 3072, 1024);
  // Stage B
  prep_kernel<<<1296, b256, 0, stream>>>(qkv, vtb, wo, woT, mask, addm, flags);
  attn_kernel<<<dim3(16, 32), b256, 0, stream>>>(qkv, vtb, addm, flags, ctxb);
  // Stage C
  gemm64_bt_kernel<1><<<dim3(16, 32), b256, 0, stream>>>(ctxb, woT, x1, nullptr, x,
                                                         4096, 1024, 1024);
  // Stage D
  ln_kernel<<<4096, b256, 0, stream>>>(x1, xn2, alpha2, bias2);
  // Stage E: FFN in 2 hidden-halves of 2048
  for (int c = 0; c < 2; ++c) {
    wtrans_kernel<<<1024, b256, 0, stream>>>(w1 + c * 2048,
                                             w2 + (size_t)c * 2048 * 1024,
                                             w1Th, w2Th);
    gemm_bt_k64_kernel<2><<<dim3(16, 32), b256, 0, stream>>>(xn2, w1Th, hc,
                                                             b1 + c * 2048, nullptr,
                                                             4096, 2048, 1024);
    gemm64_bt_kernel<3><<<dim3(16, 32), b256, 0, stream>>>(hc, w2Th, x1, nullptr,
                                                           nullptr, 4096, 1024, 2048);
  }
  // Stage F
  bias_add_kernel<<<4096, b256, 0, stream>>>(x1, b2, (float*)d_out);
}

// Round 9
// 383.574 us; speedup vs baseline: 1.0317x; 1.0317x over previous
//
#include <hip/hip_runtime.h>
#include <hip/hip_bf16.h>

typedef __attribute__((ext_vector_type(8))) short bf16x8;
typedef __attribute__((ext_vector_type(4))) short short4v;
typedef __attribute__((ext_vector_type(4))) float floatx4;

#define MFMA16(A, B, C) __builtin_amdgcn_mfma_f32_16x16x32_bf16((A), (B), (C), 0, 0, 0)

__device__ inline short bf16bits(float f) {
  __hip_bfloat16 h = __float2bfloat16(f);
  return *reinterpret_cast<short*>(&h);
}
// HW packed f32->bf16 (RNE). No builtin on gfx950 (m240) -> inline asm.
__device__ inline unsigned cvtpk(float lo, float hi) {
  unsigned r;
  asm("v_cvt_pk_bf16_f32 %0, %1, %2" : "=v"(r) : "v"(lo), "v"(hi));
  return r;
}
typedef __attribute__((address_space(3))) char lds_char;
typedef __attribute__((address_space(1))) const char glob_char;
__device__ inline void gll16(const void* g, void* l) {
  __builtin_amdgcn_global_load_lds((glob_char*)g, (lds_char*)l, 16, 0, 0);
}

// ---------------------------------------------------------------------------
// Merged ln1 + wqkv transpose (round 7).
// ---------------------------------------------------------------------------
__global__ __launch_bounds__(256) void ln_qkvtrans_kernel(
    const float* __restrict__ x, __hip_bfloat16* __restrict__ y,
    const float* __restrict__ alpha_p, const float* __restrict__ bias_p,
    const float* __restrict__ wq, const float* __restrict__ wk,
    const float* __restrict__ wv, __hip_bfloat16* __restrict__ wqkvT) {
  __shared__ __align__(16) __hip_bfloat16 tile[64][72];
  const int bid = blockIdx.x;
  const int t = threadIdx.x;
  if (bid < 4096) {
    __shared__ float sred[8];
    const float* xr = x + (long)bid * 1024;
    float v[4];
#pragma unroll
    for (int i = 0; i < 4; i++) v[i] = xr[t * 4 + i];
    float sum = 0.f, sq = 0.f;
#pragma unroll
    for (int i = 0; i < 4; i++) { sum += v[i]; sq += v[i] * v[i]; }
#pragma unroll
    for (int off = 32; off; off >>= 1) {
      sum += __shfl_down(sum, off);
      sq += __shfl_down(sq, off);
    }
    if ((t & 63) == 0) { sred[(t >> 6) * 2] = sum; sred[(t >> 6) * 2 + 1] = sq; }
    __syncthreads();
    sum = sred[0] + sred[2] + sred[4] + sred[6];
    sq = sred[1] + sred[3] + sred[5] + sred[7];
    const float mean = sum * (1.f / 1024.f);
    float var = (sq - 1024.f * mean * mean) * (1.f / 1023.f);
    var = fmaxf(var, 0.f);
    const float denom = sqrtf(var) + 1e-5f;
    const float sc = alpha_p[0] / denom;
    const float beta = bias_p[0];
    __hip_bfloat16* yr = y + (long)bid * 1024;
#pragma unroll
    for (int i = 0; i < 4; i++) yr[t * 4 + i] = __float2bfloat16((v[i] - mean) * sc + beta);
  } else {
    const int tt = bid - 4096;
    const int which = tt >> 8;
    const float* src = which == 0 ? wq : (which == 1 ? wk : wv);
    __hip_bfloat16* dst = wqkvT + (size_t)which * 1024 * 1024;
    const long r0 = (long)((tt >> 4) & 15) * 64, c0 = (long)(tt & 15) * 64;
    for (int i = t; i < 1024; i += 256) {
      int r = i >> 4, c4 = (i & 15) * 4;
      float4 f = *(const float4*)&src[(r0 + r) * 1024 + c0 + c4];
      short4v s;
      s[0] = bf16bits(f.x); s[1] = bf16bits(f.y);
      s[2] = bf16bits(f.z); s[3] = bf16bits(f.w);
      *(short4v*)&tile[r][c4] = s;
    }
    __syncthreads();
    for (int i = t; i < 512; i += 256) {
      int c = i >> 3, r8 = (i & 7) * 8;
      bf16x8 sv;
#pragma unroll
      for (int j = 0; j < 8; j++) sv[j] = *reinterpret_cast<const short*>(&tile[r8 + j][c]);
      *(bf16x8*)&dst[(c0 + c) * 1024 + r0 + r8] = sv;
    }
  }
}

// ---------------------------------------------------------------------------
// Merged stage-B prep kernel (round 6).
// ---------------------------------------------------------------------------
__global__ __launch_bounds__(256) void prep_kernel(
    const __hip_bfloat16* __restrict__ qkv, __hip_bfloat16* __restrict__ vt,
    const float* __restrict__ wo, __hip_bfloat16* __restrict__ woT,
    const int* __restrict__ mask, float* __restrict__ addm,
    int* __restrict__ flags) {
  __shared__ __align__(16) __hip_bfloat16 tile[64][72];
  __shared__ int ok[4];
  const int bid = blockIdx.x;
  if (bid < 1024) {
    const int bh = bid >> 5, b = bh >> 4, h = bh & 15;
    const long s0 = (long)(bid & 31) * 64;
    const __hip_bfloat16* src = qkv + ((long)b * 2048 + s0) * 3072 + 2048 + h * 64;
    for (int i = threadIdx.x; i < 512; i += 256) {
      int s = i >> 3, d8 = (i & 7) * 8;
      *(uint4*)&tile[s][d8] = *(const uint4*)&src[(long)s * 3072 + d8];
    }
    __syncthreads();
    __hip_bfloat16* dstb = vt + (long)bh * 64 * 2048 + s0;
    for (int i = threadIdx.x; i < 512; i += 256) {
      int d = i >> 3, s8 = (i & 7) * 8;
      bf16x8 sv;
#pragma unroll
      for (int j = 0; j < 8; j++) sv[j] = *reinterpret_cast<const short*>(&tile[s8 + j][d]);
      *(bf16x8*)&dstb[(long)d * 2048 + s8] = sv;
    }
  } else if (bid < 1280) {
    const int t = bid - 1024;
    const long r0 = (long)(t >> 4) * 64, c0 = (long)(t & 15) * 64;
    for (int i = threadIdx.x; i < 1024; i += 256) {
      int r = i >> 4, c4 = (i & 15) * 4;
      float4 f = *(const float4*)&wo[(r0 + r) * 1024 + c0 + c4];
      short4v s;
      s[0] = bf16bits(f.x); s[1] = bf16bits(f.y);
      s[2] = bf16bits(f.z); s[3] = bf16bits(f.w);
      *(short4v*)&tile[r][c4] = s;
    }
    __syncthreads();
    for (int i = threadIdx.x; i < 512; i += 256) {
      int c = i >> 3, r8 = (i & 7) * 8;
      bf16x8 sv;
#pragma unroll
      for (int j = 0; j < 8; j++) sv[j] = *reinterpret_cast<const short*>(&tile[r8 + j][c]);
      *(bf16x8*)&woT[(c0 + c) * 1024 + r0 + r8] = sv;
    }
  } else {
    const int i = (bid - 1280) * 256 + threadIdx.x;
    const int mv = mask[i];
    addm[i] = mv ? 0.f : -1e30f;
    const unsigned long long bal = __ballot(mv != 0);
    if ((threadIdx.x & 63) == 0) ok[threadIdx.x >> 6] = (bal == ~0ull) ? 1 : 0;
    __syncthreads();
    if (threadIdx.x == 0) flags[bid - 1280] = ok[0] & ok[1] & ok[2] & ok[3];
  }
}

// ---------------------------------------------------------------------------
// Round 9: merged ln2 + FFN weight transpose for half c=0 — one launch
// replaces 2. bid<4096: LN row of x1 -> xn2; else wtrans(c=0) blocks.
// ---------------------------------------------------------------------------
__global__ __launch_bounds__(256) void ln2_wtrans_kernel(
    const float* __restrict__ x1, __hip_bfloat16* __restrict__ xn2,
    const float* __restrict__ alpha_p, const float* __restrict__ bias_p,
    const float* __restrict__ w1c, const float* __restrict__ w2c,
    __hip_bfloat16* __restrict__ w1Th, __hip_bfloat16* __restrict__ w2Th) {
  __shared__ __align__(16) __hip_bfloat16 tile[64][72];
  const int bid = blockIdx.x;
  const int t = threadIdx.x;
  if (bid < 4096) {
    __shared__ float sred[8];
    const float* xr = x1 + (long)bid * 1024;
    float v[4];
#pragma unroll
    for (int i = 0; i < 4; i++) v[i] = xr[t * 4 + i];
    float sum = 0.f, sq = 0.f;
#pragma unroll
    for (int i = 0; i < 4; i++) { sum += v[i]; sq += v[i] * v[i]; }
#pragma unroll
    for (int off = 32; off; off >>= 1) {
      sum += __shfl_down(sum, off);
      sq += __shfl_down(sq, off);
    }
    if ((t & 63) == 0) { sred[(t >> 6) * 2] = sum; sred[(t >> 6) * 2 + 1] = sq; }
    __syncthreads();
    sum = sred[0] + sred[2] + sred[4] + sred[6];
    sq = sred[1] + sred[3] + sred[5] + sred[7];
    const float mean = sum * (1.f / 1024.f);
    float var = (sq - 1024.f * mean * mean) * (1.f / 1023.f);
    var = fmaxf(var, 0.f);
    const float denom = sqrtf(var) + 1e-5f;
    const float sc = alpha_p[0] / denom;
    const float beta = bias_p[0];
    __hip_bfloat16* yr = xn2 + (long)bid * 1024;
#pragma unroll
    for (int i = 0; i < 4; i++) yr[t * 4 + i] = __float2bfloat16((v[i] - mean) * sc + beta);
  } else {
    const int wb = bid - 4096;
    const float* src;
    __hip_bfloat16* dst;
    int R, ldS;
    long r0, c0;
    if (wb < 512) {
      src = w1c; dst = w1Th; R = 1024; ldS = 4096;
      r0 = (long)(wb >> 5) * 64; c0 = (long)(wb & 31) * 64;
    } else {
      const int t2 = wb - 512;
      src = w2c; dst = w2Th; R = 2048; ldS = 1024;
      r0 = (long)(t2 >> 4) * 64; c0 = (long)(t2 & 15) * 64;
    }
    for (int i = t; i < 1024; i += 256) {
      int r = i >> 4, c4 = (i & 15) * 4;
      float4 f = *(const float4*)&src[(r0 + r) * ldS + c0 + c4];
      short4v s;
      s[0] = bf16bits(f.x); s[1] = bf16bits(f.y);
      s[2] = bf16bits(f.z); s[3] = bf16bits(f.w);
      *(short4v*)&tile[r][c4] = s;
    }
    __syncthreads();
    for (int i = t; i < 512; i += 256) {
      int c = i >> 3, r8 = (i & 7) * 8;
      bf16x8 sv;
#pragma unroll
      for (int j = 0; j < 8; j++) sv[j] = *reinterpret_cast<const short*>(&tile[r8 + j][c]);
      *(bf16x8*)&dst[(c0 + c) * R + r0 + r8] = sv;
    }
  }
}

// ---------------------------------------------------------------------------
// Merged per-half FFN weight transpose (round 6) — used for c=1.
// ---------------------------------------------------------------------------
__global__ __launch_bounds__(256) void wtrans_kernel(
    const float* __restrict__ w1c, const float* __restrict__ w2c,
    __hip_bfloat16* __restrict__ w1Th, __hip_bfloat16* __restrict__ w2Th) {
  __shared__ __align__(16) __hip_bfloat16 tile[64][72];
  const int bid = blockIdx.x;
  const float* src;
  __hip_bfloat16* dst;
  int R, ldS;
  long r0, c0;
  if (bid < 512) {
    src = w1c; dst = w1Th; R = 1024; ldS = 4096;
    r0 = (long)(bid >> 5) * 64; c0 = (long)(bid & 31) * 64;
  } else {
    const int t = bid - 512;
    src = w2c; dst = w2Th; R = 2048; ldS = 1024;
    r0 = (long)(t >> 4) * 64; c0 = (long)(t & 15) * 64;
  }
  for (int i = threadIdx.x; i < 1024; i += 256) {
    int r = i >> 4, c4 = (i & 15) * 4;
    float4 f = *(const float4*)&src[(r0 + r) * ldS + c0 + c4];
    short4v s;
    s[0] = bf16bits(f.x); s[1] = bf16bits(f.y);
    s[2] = bf16bits(f.z); s[3] = bf16bits(f.w);
    *(short4v*)&tile[r][c4] = s;
  }
  __syncthreads();
  for (int i = threadIdx.x; i < 512; i += 256) {
    int c = i >> 3, r8 = (i & 7) * 8;
    bf16x8 sv;
#pragma unroll
    for (int j = 0; j < 8; j++) sv[j] = *reinterpret_cast<const short*>(&tile[r8 + j][c]);
    *(bf16x8*)&dst[(c0 + c) * R + r0 + r8] = sv;
  }
}

// ---------------------------------------------------------------------------
// d_out = x1 + b2 (broadcast over rows), fp32
// ---------------------------------------------------------------------------
__global__ __launch_bounds__(256) void bias_add_kernel(
    const float* __restrict__ x1, const float* __restrict__ b2,
    float* __restrict__ out) {
  const int i = (blockIdx.x * 256 + threadIdx.x) * 4;
  float4 v = *(const float4*)&x1[i];
  const float4 bb = *(const float4*)&b2[i & 1023];
  v.x += bb.x; v.y += bb.y; v.z += bb.z; v.w += bb.w;
  *(float4*)&out[i] = v;
}

// ---------------------------------------------------------------------------
// bf16 GEMM, B pre-transposed: 128x128 tile, BK=32, dbuf + XCD swizzle.
// Round 9: restored as the qkv GEMM (768 blocks = 3/CU beats BK=64's 2/CU —
// r8 measured +11 us from that switch; occupancy > barrier-halving here).
// ---------------------------------------------------------------------------
template <int EPI>
__global__ __launch_bounds__(256) void gemm_bt_kernel(
    const __hip_bfloat16* __restrict__ A, const __hip_bfloat16* __restrict__ Bt,
    void* __restrict__ Cv, const float* __restrict__ bias,
    const float* __restrict__ res, int M, int N, int K) {
  __shared__ __align__(16) __hip_bfloat16 lA[2][128 * 32];
  __shared__ __align__(16) __hip_bfloat16 lB[2][128 * 32];
  const int tid = threadIdx.x;
  const int wave = tid >> 6, lane = tid & 63;
  const int quad = lane >> 4, l16 = lane & 15;
  const int wm = wave >> 1, wn = wave & 1;

  const int gx = gridDim.x;
  const int nwg = gx * gridDim.y;
  int bid = blockIdx.y * gx + blockIdx.x;
  bid = (bid & 7) * (nwg >> 3) + (bid >> 3);
  const long m0 = (long)(bid / gx) * 128;
  const long n0 = (long)(bid % gx) * 128;

  const int rA0 = tid >> 2, cA0 = (tid & 3) * 8;
  const int rA1 = (tid + 256) >> 2, cA1 = ((tid + 256) & 3) * 8;

  floatx4 acc[4][4];
#pragma unroll
  for (int i = 0; i < 4; i++)
#pragma unroll
    for (int j = 0; j < 4; j++) acc[i][j] = (floatx4){0.f, 0.f, 0.f, 0.f};

  const __hip_bfloat16* Ab = A + m0 * K;
  const __hip_bfloat16* Bb = Bt + n0 * K;

  gll16(&Ab[(long)rA0 * K + cA0], &lA[0][wave * 512]);
  gll16(&Ab[(long)rA1 * K + cA1], &lA[0][2048 + wave * 512]);
  gll16(&Bb[(long)rA0 * K + cA0], &lB[0][wave * 512]);
  gll16(&Bb[(long)rA1 * K + cA1], &lB[0][2048 + wave * 512]);

  int cur = 0;
  for (int k0 = 0; k0 < K; k0 += 32) {
    __syncthreads();
    if (k0 + 32 < K) {
      const int nxt = cur ^ 1;
      gll16(&Ab[(long)rA0 * K + k0 + 32 + cA0], &lA[nxt][wave * 512]);
      gll16(&Ab[(long)rA1 * K + k0 + 32 + cA1], &lA[nxt][2048 + wave * 512]);
      gll16(&Bb[(long)rA0 * K + k0 + 32 + cA0], &lB[nxt][wave * 512]);
      gll16(&Bb[(long)rA1 * K + k0 + 32 + cA1], &lB[nxt][2048 + wave * 512]);
    }
    bf16x8 af[4], bfr[4];
#pragma unroll
    for (int mi = 0; mi < 4; mi++)
      af[mi] = *(const bf16x8*)&lA[cur][(wm * 64 + mi * 16 + l16) * 32 + quad * 8];
#pragma unroll
    for (int ni = 0; ni < 4; ni++)
      bfr[ni] = *(const bf16x8*)&lB[cur][(wn * 64 + ni * 16 + l16) * 32 + quad * 8];
#pragma unroll
    for (int mi = 0; mi < 4; mi++)
#pragma unroll
      for (int ni = 0; ni < 4; ni++)
        acc[mi][ni] = MFMA16(af[mi], bfr[ni], acc[mi][ni]);
    cur ^= 1;
  }

#pragma unroll
  for (int mi = 0; mi < 4; mi++) {
#pragma unroll
    for (int ni = 0; ni < 4; ni++) {
#pragma unroll
      for (int r = 0; r < 4; r++) {
        const long row = m0 + wm * 64 + mi * 16 + quad * 4 + r;
        const long col = n0 + wn * 64 + ni * 16 + l16;
        const long idx = row * N + col;
        float v = acc[mi][ni][r];
        if (EPI == 0) {
          ((__hip_bfloat16*)Cv)[idx] = __float2bfloat16(v);
        } else if (EPI == 1) {
          ((float*)Cv)[idx] = v + res[idx];
        } else if (EPI == 2) {
          v += bias[col];
          ((__hip_bfloat16*)Cv)[idx] = __float2bfloat16(fmaxf(v, 0.f));
        } else if (EPI == 3) {
          float* Cf = (float*)Cv;
          Cf[idx] = Cf[idx] + v;
        }
      }
    }
  }
}

// ---------------------------------------------------------------------------
// 128x128 tile, BK=64, XOR-swizzled LDS (round 7). Used for ffn1 only
// (512-block grid caps residency at 2/CU anyway, so BK=64 is free there).
// ---------------------------------------------------------------------------
template <int EPI>
__global__ __launch_bounds__(256) void gemm_bt_k64_kernel(
    const __hip_bfloat16* __restrict__ A, const __hip_bfloat16* __restrict__ Bt,
    void* __restrict__ Cv, const float* __restrict__ bias,
    const float* __restrict__ res, int M, int N, int K) {
  __shared__ __align__(16) __hip_bfloat16 lA[2][128 * 64];
  __shared__ __align__(16) __hip_bfloat16 lB[2][128 * 64];
  const int tid = threadIdx.x;
  const int wave = tid >> 6, lane = tid & 63;
  const int quad = lane >> 4, l16 = lane & 15;
  const int wm = wave >> 1, wn = wave & 1;

  const int gx = gridDim.x;
  const int nwg = gx * gridDim.y;
  int bid = blockIdx.y * gx + blockIdx.x;
  bid = (bid & 7) * (nwg >> 3) + (bid >> 3);
  const long m0 = (long)(bid / gx) * 128;
  const long n0 = (long)(bid % gx) * 128;

  const int srow = lane >> 3;               // row within 8-row chunk
  const int cg = (lane & 7) ^ srow;         // pre-swizzled global k-group

  floatx4 acc[4][4];
#pragma unroll
  for (int i = 0; i < 4; i++)
#pragma unroll
    for (int j = 0; j < 4; j++) acc[i][j] = (floatx4){0.f, 0.f, 0.f, 0.f};

  const __hip_bfloat16* Ab = A + m0 * K;
  const __hip_bfloat16* Bb = Bt + n0 * K;

#pragma unroll
  for (int j = 0; j < 4; ++j) {
    const int c = wave + j * 4;
    gll16(&Ab[(long)(c * 8 + srow) * K + cg * 8], &lA[0][c * 512]);
    gll16(&Bb[(long)(c * 8 + srow) * K + cg * 8], &lB[0][c * 512]);
  }

  int cur = 0;
  for (int k0 = 0; k0 < K; k0 += 64) {
    __syncthreads();
    if (k0 + 64 < K) {
      const int nxt = cur ^ 1;
#pragma unroll
      for (int j = 0; j < 4; ++j) {
        const int c = wave + j * 4;
        gll16(&Ab[(long)(c * 8 + srow) * K + k0 + 64 + cg * 8], &lA[nxt][c * 512]);
        gll16(&Bb[(long)(c * 8 + srow) * K + k0 + 64 + cg * 8], &lB[nxt][c * 512]);
      }
    }
#pragma unroll
    for (int ks = 0; ks < 2; ++ks) {
      bf16x8 af[4], bfr[4];
#pragma unroll
      for (int mi = 0; mi < 4; mi++) {
        const int row = wm * 64 + mi * 16 + l16;
        af[mi] = *(const bf16x8*)&lA[cur][row * 64 +
                                          (((ks * 4 + quad) ^ (l16 & 7)) * 8)];
      }
#pragma unroll
      for (int ni = 0; ni < 4; ni++) {
        const int row = wn * 64 + ni * 16 + l16;
        bfr[ni] = *(const bf16x8*)&lB[cur][row * 64 +
                                           (((ks * 4 + quad) ^ (l16 & 7)) * 8)];
      }
#pragma unroll
      for (int mi = 0; mi < 4; mi++)
#pragma unroll
        for (int ni = 0; ni < 4; ni++)
          acc[mi][ni] = MFMA16(af[mi], bfr[ni], acc[mi][ni]);
    }
    cur ^= 1;
  }

#pragma unroll
  for (int mi = 0; mi < 4; mi++) {
#pragma unroll
    for (int ni = 0; ni < 4; ni++) {
#pragma unroll
      for (int r = 0; r < 4; r++) {
        const long row = m0 + wm * 64 + mi * 16 + quad * 4 + r;
        const long col = n0 + wn * 64 + ni * 16 + l16;
        const long idx = row * N + col;
        float v = acc[mi][ni][r];
        if (EPI == 0) {
          ((__hip_bfloat16*)Cv)[idx] = __float2bfloat16(v);
        } else if (EPI == 1) {
          ((float*)Cv)[idx] = v + res[idx];
        } else if (EPI == 2) {
          v += bias[col];
          ((__hip_bfloat16*)Cv)[idx] = __float2bfloat16(fmaxf(v, 0.f));
        } else if (EPI == 3) {
          float* Cf = (float*)Cv;
          Cf[idx] = Cf[idx] + v;
        }
      }
    }
  }
}

// ---------------------------------------------------------------------------
// 128x64-tile variant for N=1024 GEMMs (wo, ffn2): BK=64 swizzled (round 6).
// ---------------------------------------------------------------------------
template <int EPI>
__global__ __launch_bounds__(256) void gemm64_bt_kernel(
    const __hip_bfloat16* __restrict__ A, const __hip_bfloat16* __restrict__ Bt,
    void* __restrict__ Cv, const float* __restrict__ bias,
    const float* __restrict__ res, int M, int N, int K) {
  __shared__ __align__(16) __hip_bfloat16 lA[2][128 * 64];
  __shared__ __align__(16) __hip_bfloat16 lB[2][64 * 64];
  const int tid = threadIdx.x;
  const int wave = tid >> 6, lane = tid & 63;
  const int quad = lane >> 4, l16 = lane & 15;
  const int wm = wave >> 1, wn = wave & 1;

  const int gx = gridDim.x;
  const int nwg = gx * gridDim.y;
  int bid = blockIdx.y * gx + blockIdx.x;
  bid = (bid & 7) * (nwg >> 3) + (bid >> 3);
  const long m0 = (long)(bid / gx) * 128;
  const long n0 = (long)(bid % gx) * 64;

  const int srow = lane >> 3;
  const int cg = (lane & 7) ^ srow;

  floatx4 acc[4][2];
#pragma unroll
  for (int i = 0; i < 4; i++)
#pragma unroll
    for (int j = 0; j < 2; j++) acc[i][j] = (floatx4){0.f, 0.f, 0.f, 0.f};

  const __hip_bfloat16* Ab = A + m0 * K;
  const __hip_bfloat16* Bb = Bt + n0 * K;

#pragma unroll
  for (int j = 0; j < 4; ++j) {
    const int c = wave + j * 4;
    gll16(&Ab[(long)(c * 8 + srow) * K + cg * 8], &lA[0][c * 512]);
  }
#pragma unroll
  for (int j = 0; j < 2; ++j) {
    const int c = wave + j * 4;
    gll16(&Bb[(long)(c * 8 + srow) * K + cg * 8], &lB[0][c * 512]);
  }

  int cur = 0;
  for (int k0 = 0; k0 < K; k0 += 64) {
    __syncthreads();
    if (k0 + 64 < K) {
      const int nxt = cur ^ 1;
#pragma unroll
      for (int j = 0; j < 4; ++j) {
        const int c = wave + j * 4;
        gll16(&Ab[(long)(c * 8 + srow) * K + k0 + 64 + cg * 8], &lA[nxt][c * 512]);
      }
#pragma unroll
      for (int j = 0; j < 2; ++j) {
        const int c = wave + j * 4;
        gll16(&Bb[(long)(c * 8 + srow) * K + k0 + 64 + cg * 8], &lB[nxt][c * 512]);
      }
    }
#pragma unroll
    for (int ks = 0; ks < 2; ++ks) {
      bf16x8 af[4], bfr[2];
#pragma unroll
      for (int mi = 0; mi < 4; mi++) {
        const int row = wm * 64 + mi * 16 + l16;
        af[mi] = *(const bf16x8*)&lA[cur][row * 64 +
                                          (((ks * 4 + quad) ^ (l16 & 7)) * 8)];
      }
#pragma unroll
      for (int ni = 0; ni < 2; ni++) {
        const int row = wn * 32 + ni * 16 + l16;
        bfr[ni] = *(const bf16x8*)&lB[cur][row * 64 +
                                           (((ks * 4 + quad) ^ (l16 & 7)) * 8)];
      }
#pragma unroll
      for (int mi = 0; mi < 4; mi++)
#pragma unroll
        for (int ni = 0; ni < 2; ni++)
          acc[mi][ni] = MFMA16(af[mi], bfr[ni], acc[mi][ni]);
    }
    cur ^= 1;
  }

#pragma unroll
  for (int mi = 0; mi < 4; mi++) {
#pragma unroll
    for (int ni = 0; ni < 2; ni++) {
#pragma unroll
      for (int r = 0; r < 4; r++) {
        const long row = m0 + wm * 64 + mi * 16 + quad * 4 + r;
        const long col = n0 + wn * 32 + ni * 16 + l16;
        const long idx = row * N + col;
        float v = acc[mi][ni][r];
        if (EPI == 1) {
          ((float*)Cv)[idx] = v + res[idx];
        } else if (EPI == 3) {
          float* Cf = (float*)Cv;
          Cf[idx] = Cf[idx] + v;
        }
      }
    }
  }
}

// ---------------------------------------------------------------------------
// Flash attention — round 7 structure restored (64 q-rows/block, 4 blocks/CU;
// r8's 128-row variant was dispatch-neutral with worse occupancy margin).
// Round 9 addition: XCD-chunked block swizzle (grid 1024 %8==0) — consecutive
// logical blocks share one head's K/V panels (512 KB; 4 heads = 2 MB fits the
// 4 MB per-XCD L2), so K/V reads become XCD-local instead of replicated.
// ---------------------------------------------------------------------------
__global__ __launch_bounds__(256) void attn_kernel(
    const __hip_bfloat16* __restrict__ qkv, const __hip_bfloat16* __restrict__ vt,
    const float* __restrict__ addm, const int* __restrict__ flags,
    __hip_bfloat16* __restrict__ ctx) {
  __shared__ __align__(16) __hip_bfloat16 lK[2][64 * 64];
  __shared__ __align__(16) __hip_bfloat16 lV[2][64 * 64];
  __shared__ __align__(16) __hip_bfloat16 lP[4][16 * 64];  // wave-private P^T
  const int tid = threadIdx.x, wave = tid >> 6, lane = tid & 63;
  const int quad = lane >> 4, l16 = lane & 15;
  // XCD-chunked swizzle over the flat 1024-block grid
  const int nwg = gridDim.x * gridDim.y;
  int bid0 = blockIdx.y * gridDim.x + blockIdx.x;
  bid0 = (bid0 & 7) * (nwg >> 3) + (bid0 >> 3);
  const int bh = bid0 >> 5, b = bh >> 4, h = bh & 15;
  const int q0 = (bid0 & 31) * 64 + wave * 16;
  const float cs = 0.18033688011112042f;   // log2(e)/sqrt(64)
  const float inv_cs = 5.545177444479562f; // sqrt(64)/log2(e)

  const __hip_bfloat16* kb = qkv + (long)b * 2048 * 3072 + 1024 + h * 64;
  const __hip_bfloat16* vb = vt + (long)bh * 64 * 2048;
  const float* am = addm + b * 2048;

  int fm = 1;
#pragma unroll
  for (int i = 0; i < 8; ++i) fm &= flags[b * 8 + i];
  const bool fast = (fm != 0);

  const long qoff = ((long)b * 2048 + q0 + l16) * 3072 + h * 64;
  const bf16x8 bq0 = *(const bf16x8*)&qkv[qoff + quad * 8];
  const bf16x8 bq1 = *(const bf16x8*)&qkv[qoff + 32 + quad * 8];

  const int srow = lane >> 3;
  const int cslot = lane & 7;
  const int cg = cslot ^ srow;
  const int rbase = wave * 16 + srow;

  // P-buffer addresses (bytes within this wave's 2 KB region)
  char* const pbase = (char*)&lP[wave][0];
  const int prow = l16 * 128;
  const int pswz = l16 & 7;

  floatx4 o[4];
#pragma unroll
  for (int mi = 0; mi < 4; mi++) o[mi] = (floatx4){0.f, 0.f, 0.f, 0.f};
  float mrow = 10.0f, lrow = 0.f;  // mrow in log2 units (score*cs domain)

  // prologue: stage tile 0 into buffer 0
#pragma unroll
  for (int j = 0; j < 2; ++j) {
    const int rloc = rbase + j * 8;
    gll16(kb + (long)rloc * 3072 + cg * 8, &lK[0][(wave * 16 + j * 8) * 64]);
    gll16(vb + (long)rloc * 2048 + cg * 8, &lV[0][(wave * 16 + j * 8) * 64]);
  }

  int cur = 0;
  for (int t = 0; t < 32; ++t) {
    __syncthreads();
    if (t + 1 < 32) {
      const int nxt = cur ^ 1;
#pragma unroll
      for (int j = 0; j < 2; ++j) {
        const int rloc = rbase + j * 8;
        gll16(kb + (long)((t + 1) * 64 + rloc) * 3072 + cg * 8,
              &lK[nxt][(wave * 16 + j * 8) * 64]);
        gll16(vb + (long)rloc * 2048 + (t + 1) * 64 + cg * 8,
              &lV[nxt][(wave * 16 + j * 8) * 64]);
      }
    }
    const __hip_bfloat16* lKc = lK[cur];
    const __hip_bfloat16* lVc = lV[cur];

    floatx4 c[4];
    __builtin_amdgcn_s_setprio(1);
#pragma unroll
    for (int g = 0; g < 4; ++g) {
      const bf16x8 a0 =
          *(const bf16x8*)&lKc[(g * 16 + l16) * 64 + ((quad) ^ (l16 & 7)) * 8];
      const bf16x8 a1 =
          *(const bf16x8*)&lKc[(g * 16 + l16) * 64 + ((4 + quad) ^ (l16 & 7)) * 8];
      floatx4 cc = {0.f, 0.f, 0.f, 0.f};
      cc = MFMA16(a0, bq0, cc);
      cc = MFMA16(a1, bq1, cc);
      c[g] = cc;
    }
    __builtin_amdgcn_s_setprio(0);

    if (!fast) {
#pragma unroll
      for (int g = 0; g < 4; ++g) {
        const float4 a4 = *(const float4*)&am[t * 64 + g * 16 + quad * 4];
        c[g][0] = fmaf(a4.x, inv_cs, c[g][0]);
        c[g][1] = fmaf(a4.y, inv_cs, c[g][1]);
        c[g][2] = fmaf(a4.z, inv_cs, c[g][2]);
        c[g][3] = fmaf(a4.w, inv_cs, c[g][3]);
      }
    }

    // speculative P with the OLD running max — off the max-reduce chain
    const float mneg = -mrow;
    float p[4][4];
#pragma unroll
    for (int g = 0; g < 4; ++g)
#pragma unroll
      for (int r = 0; r < 4; ++r)
        p[g][r] = __builtin_amdgcn_exp2f(fmaf(c[g][r], cs, mneg));

    // pack P and write to the wave-private LDS transpose buffer.
#pragma unroll
    for (int g = 0; g < 4; ++g) {
      uint2 w2;
      w2.x = cvtpk(p[g][0], p[g][1]);
      w2.y = cvtpk(p[g][2], p[g][3]);
      const int slot16 = (g * 2 + (quad >> 1)) ^ pswz;
      *(uint2*)(pbase + prow + (slot16 << 4) + ((quad & 1) << 3)) = w2;
    }

    // tile row-max reduce — concurrent with PV below
    const float m0 = fmaxf(fmaxf(c[0][0], c[0][1]), c[0][2]);
    const float m1 = fmaxf(fmaxf(c[0][3], c[1][0]), c[1][1]);
    const float m2 = fmaxf(fmaxf(c[1][2], c[1][3]), c[2][0]);
    const float m3 = fmaxf(fmaxf(c[2][1], c[2][2]), c[2][3]);
    const float m4 = fmaxf(fmaxf(c[3][0], c[3][1]), c[3][2]);
    float tm = fmaxf(fmaxf(fmaxf(m0, m1), fmaxf(m2, m3)), fmaxf(m4, c[3][3]));
    tm = fmaxf(tm, __shfl_xor(tm, 16));
    tm = fmaxf(tm, __shfl_xor(tm, 32));
    const float tms = tm * cs;

    const float s0 = (p[0][0] + p[0][1]) + (p[0][2] + p[0][3]);
    const float s1 = (p[1][0] + p[1][1]) + (p[1][2] + p[1][3]);
    const float s2 = (p[2][0] + p[2][1]) + (p[2][2] + p[2][3]);
    const float s3 = (p[3][0] + p[3][1]) + (p[3][2] + p[3][3]);
    float rs = (s0 + s1) + (s2 + s3);
    rs += __shfl_xor(rs, 16);
    rs += __shfl_xor(rs, 32);

    // PV: B-fragment = one swizzled b128 from the wave P-buffer
#pragma unroll
    for (int ss = 0; ss < 2; ++ss) {
      const bf16x8 bp = *(const bf16x8*)(pbase + prow +
                                         ((((ss << 2) + quad) ^ pswz) << 4));
      __builtin_amdgcn_s_setprio(1);
#pragma unroll
      for (int mi = 0; mi < 4; ++mi) {
        const bf16x8 av = *(const bf16x8*)&lVc[(mi * 16 + l16) * 64 +
                                               ((ss * 4 + quad) ^ (l16 & 7)) * 8];
        o[mi] = MFMA16(av, bp, o[mi]);
      }
      __builtin_amdgcn_s_setprio(0);
    }

    lrow += rs;
    if (__any(tms > mrow + 8.f)) {
      const float mnew = fmaxf(mrow, tms);
      const float alpha = __builtin_amdgcn_exp2f(mrow - mnew);
      mrow = mnew;
      lrow *= alpha;
#pragma unroll
      for (int mi = 0; mi < 4; mi++) o[mi] *= alpha;
    }
    cur ^= 1;
  }

  const float inv_l = 1.f / lrow;
  const long cb = ((long)b * 2048 + q0 + l16) * 1024 + h * 64;
#pragma unroll
  for (int mi = 0; mi < 4; mi++) {
    uint2 st;
    st.x = cvtpk(o[mi][0] * inv_l, o[mi][1] * inv_l);
    st.y = cvtpk(o[mi][2] * inv_l, o[mi][3] * inv_l);
    *(uint2*)&ctx[cb + mi * 16 + quad * 4] = st;
  }
}

// ---------------------------------------------------------------------------
// ws plan (peak 32 MiB) + d_out (16 MiB) as scratch:
//  A: ln_qkvtrans: ln1 x->xn(d_out[0,8)) + wqkvT ws[24,30);
//     qkv-gemm (BK=32) -> qkv ws[0,24)
//  B: prep: vtrans -> vtb ws[24,32); woT -> d_out[8,10); mask -> addm+flags;
//     attn (XCD-swizzled) -> ctxb(d_out[0,8))
//  C: wo-gemm64(ctxb,woT)+x -> x1 f32 ws[0,16)  (EPI1)
//  D: ln2_wtrans (ONE launch): ln2 x1->xn2(d_out[0,8)) + wtrans(c=0)
//     -> w1Th d_out[8,12) / w2Th d_out[12,16)   [addm dead after attn]
//  E: ffn1-k64(c=0) -> hc ws[16,32); ffn2-gemm64(c=0): x1 += (EPI3);
//     wtrans(c=1); ffn1-k64(c=1); ffn2-gemm64(c=1)
//  F: bias_add: d_out = x1 + b2
//  12 launches.
// ---------------------------------------------------------------------------
extern "C" void kernel_launch(void* const* d_in, const int* in_sizes, int n_in,
                              void* d_out, int out_size, void* d_ws, size_t ws_size,
                              hipStream_t stream) {
  const float* x = (const float*)d_in[0];
  const int* mask = (const int*)d_in[1];
  const float* wq = (const float*)d_in[2];
  const float* wk = (const float*)d_in[3];
  const float* wv = (const float*)d_in[4];
  const float* wo = (const float*)d_in[5];
  const float* w1 = (const float*)d_in[6];
  const float* b1 = (const float*)d_in[7];
  const float* w2 = (const float*)d_in[8];
  const float* b2 = (const float*)d_in[9];
  const float* alpha1 = (const float*)d_in[10];
  const float* bias1 = (const float*)d_in[11];
  const float* alpha2 = (const float*)d_in[12];
  const float* bias2 = (const float*)d_in[13];

  char* ws = (char*)d_ws;
  char* dob = (char*)d_out;
  const size_t MiB = 1048576;
  __hip_bfloat16* qkv   = (__hip_bfloat16*)(ws + 0);          // [0,24)
  __hip_bfloat16* wqkvT = (__hip_bfloat16*)(ws + 24 * MiB);   // [24,30)
  __hip_bfloat16* vtb   = (__hip_bfloat16*)(ws + 24 * MiB);   // [24,32)
  float*          x1    = (float*)(ws + 0);                   // [0,16) f32
  __hip_bfloat16* hc    = (__hip_bfloat16*)(ws + 16 * MiB);   // [16,32)
  __hip_bfloat16* xn    = (__hip_bfloat16*)d_out;             // d_out[0,8) bf16
  __hip_bfloat16* ctxb  = (__hip_bfloat16*)d_out;
  __hip_bfloat16* xn2   = (__hip_bfloat16*)d_out;
  __hip_bfloat16* woT   = (__hip_bfloat16*)(dob + 8 * MiB);   // d_out[8,10)
  __hip_bfloat16* w1Th  = (__hip_bfloat16*)(dob + 8 * MiB);   // d_out[8,12)
  __hip_bfloat16* w2Th  = (__hip_bfloat16*)(dob + 12 * MiB);  // d_out[12,16)
  float*          addm  = (float*)(dob + 12 * MiB);           // d_out[12M,+16K)
  int*            flags = (int*)(dob + 12 * MiB + 16 * 1024); // 64 B after addm

  const dim3 b256(256);
  // Stage A (merged ln1 + wqkv transpose; qkv GEMM back to BK=32, 3 blk/CU)
  ln_qkvtrans_kernel<<<4864, b256, 0, stream>>>(x, xn, alpha1, bias1,
                                                wq, wk, wv, wqkvT);
  gemm_bt_kernel<0><<<dim3(24, 32), b256, 0, stream>>>(xn, wqkvT, qkv, nullptr,
                                                       nullptr, 4096, 3072, 1024);
  // Stage B
  prep_kernel<<<1296, b256, 0, stream>>>(qkv, vtb, wo, woT, mask, addm, flags);
  attn_kernel<<<dim3(32, 32), b256, 0, stream>>>(qkv, vtb, addm, flags, ctxb);
  // Stage C
  gemm64_bt_kernel<1><<<dim3(16, 32), b256, 0, stream>>>(ctxb, woT, x1, nullptr, x,
                                                         4096, 1024, 1024);
  // Stage D (merged ln2 + wtrans c=0)
  ln2_wtrans_kernel<<<5120, b256, 0, stream>>>(x1, xn2, alpha2, bias2,
                                               w1, w2, w1Th, w2Th);
  // Stage E
  gemm_bt_k64_kernel<2><<<dim3(16, 32), b256, 0, stream>>>(xn2, w1Th, hc,
                                                           b1, nullptr,
                                                           4096, 2048, 1024);
  gemm64_bt_kernel<3><<<dim3(16, 32), b256, 0, stream>>>(hc, w2Th, x1, nullptr,
                                                         nullptr, 4096, 1024, 2048);
  wtrans_kernel<<<1024, b256, 0, stream>>>(w1 + 2048,
                                           w2 + (size_t)2048 * 1024,
                                           w1Th, w2Th);
  gemm_bt_k64_kernel<2><<<dim3(16, 32), b256, 0, stream>>>(xn2, w1Th, hc,
                                                           b1 + 2048, nullptr,
                                                           4096, 2048, 1024);
  gemm64_bt_kernel<3><<<dim3(16, 32), b256, 0, stream>>>(hc, w2Th, x1, nullptr,
                                                         nullptr, 4096, 1024, 2048);
  // Stage F
  bias_add_kernel<<<4096, b256, 0, stream>>>(x1, b2, (float*)d_out);
}